// Round 18
// baseline (1041.486 us; speedup 1.0000x reference)
//
#include <hip/hip_runtime.h>
#include <hip/hip_bf16.h>
#include <math.h>

#define NND 100000   // nodes
#define EE  200000   // edges
#define LL  3        // layers
#define DD  300      // node dim
#define HH  150      // per-direction message dim

#define MPAD 100096  // 782*128
#define KP   320     // K padded (multiple of 32)
#define NPJ  640     // proj N padded
#define NUP  384     // update N padded
#define NTK  (KP / 32)

#define NB   49          // scan blocks (2048 elems each)
#define SCN  (NB * 2048) // 100352 >= MPAD+1

// P column layout (all 8B-aligned region starts, pads zero):
//  Br @ 0..149 | Bc @ 152..301 | Ar @ 304..453 | Ac @ 456..605
#define P_BR 0
#define P_BC 152
#define P_AR 304
#define P_AC 456
// RC column layout: r @ 0..149, pad, c @ 160..309, pad
#define RC_R 0
#define RC_C 160

typedef __attribute__((ext_vector_type(8))) short bf16x8;
typedef __attribute__((ext_vector_type(4))) short bf16x4;
typedef __attribute__((ext_vector_type(4))) float f32x4;

// fast GELU (tanh-form): max abs dev from exact-erf GELU ~1e-3.
__device__ __forceinline__ float gelu_exact(float x) {
    float x2 = x * x;
    float y2 = -1.5957691216f * (x + 0.044715f * x2 * x);
    float e  = __expf(y2);
    return x * __builtin_amdgcn_rcpf(1.f + e);
}
__device__ __forceinline__ unsigned short f2bf(float f) {
    union { float fv; unsigned u; } v; v.fv = f;
    unsigned r = v.u + 0x7fff + ((v.u >> 16) & 1);   // RNE (finite inputs)
    return (unsigned short)(r >> 16);
}
__device__ __forceinline__ float bf2f(unsigned short b) {
    union { unsigned u; float fv; } v; v.u = ((unsigned)b) << 16;
    return v.fv;
}

// ---------------- weight packing ----------------
__global__ __launch_bounds__(256) void pack_w(
    const float* __restrict__ Wr, const float* __restrict__ Wc,
    const float* __restrict__ Wa,
    unsigned short* __restrict__ Bt, unsigned short* __restrict__ Wat)
{
    int i = blockIdx.x * 256 + threadIdx.x;
    const int btTotal = LL * NPJ * KP;
    if (i < btTotal) {
        int l = i / (NPJ * KP);
        int rem = i % (NPJ * KP);
        int n = rem / KP;
        int k = rem % KP;
        float v = 0.f;
        if (k < DD) {
            const float* W = nullptr; int krow = k, j = -1;
            if (n >= P_BR && n < P_BR + 150)      { W = Wr; krow = 300 + k; j = n - P_BR; }
            else if (n >= P_BC && n < P_BC + 150) { W = Wc; krow = 300 + k; j = n - P_BC; }
            else if (n >= P_AR && n < P_AR + 150) { W = Wr; krow = k;       j = n - P_AR; }
            else if (n >= P_AC && n < P_AC + 150) { W = Wc; krow = k;       j = n - P_AC; }
            if (j >= 0)
                v = W[(size_t)l * 600 * 150 + (size_t)krow * 150 + j];
        }
        Bt[i] = f2bf(v);
    } else {
        int i2 = i - btTotal;
        if (i2 < NUP * KP) {
            int n = i2 / KP, k = i2 % KP;
            int kk = -1;
            if (k < 150)                 kk = k;          // r rows of Wa
            else if (k >= 160 && k < 310) kk = k - 10;    // c rows of Wa
            float v = (n < DD && kk >= 0) ? Wa[(size_t)kk * DD + n] : 0.f;
            Wat[i2] = f2bf(v);
        }
    }
}

// vbf[MPAD][KP] = bf16(x), zero pads
__global__ __launch_bounds__(256) void init_vbf(
    const float* __restrict__ x, unsigned short* __restrict__ vbf)
{
    int idx = blockIdx.x * 256 + threadIdx.x;       // chunk of 8
    int row = idx / (KP / 8);
    int gk  = (idx % (KP / 8)) * 8;
    if (row >= MPAD) return;
    unsigned short tmp[8];
    if (row < NND && gk < DD) {
        if (gk + 8 <= DD) {
            const float4* p = (const float4*)(x + (size_t)row * DD + gk);
            float4 f0 = p[0], f1 = p[1];
            tmp[0] = f2bf(f0.x); tmp[1] = f2bf(f0.y);
            tmp[2] = f2bf(f0.z); tmp[3] = f2bf(f0.w);
            tmp[4] = f2bf(f1.x); tmp[5] = f2bf(f1.y);
            tmp[6] = f2bf(f1.z); tmp[7] = f2bf(f1.w);
        } else {
            #pragma unroll
            for (int j = 0; j < 8; ++j)
                tmp[j] = (gk + j < DD) ? f2bf(x[(size_t)row * DD + gk + j]) : 0;
        }
    } else {
        #pragma unroll
        for (int j = 0; j < 8; ++j) tmp[j] = 0;
    }
    *((bf16x8*)&vbf[(size_t)row * KP + gk]) = *((bf16x8*)tmp);
}

// ---------------- CSR build ----------------
__global__ __launch_bounds__(256) void hist_deg(
    const int* __restrict__ src, const int* __restrict__ dst,
    int* __restrict__ deg)
{
    int e = blockIdx.x * 256 + threadIdx.x;
    if (e >= EE) return;
    atomicAdd(&deg[dst[e]], 1);
    atomicAdd(&deg[SCN + src[e]], 1);
}

__global__ __launch_bounds__(256) void scanA(
    const int* __restrict__ deg, int* __restrict__ off, int* __restrict__ bsum)
{
    __shared__ int ls[256];
    const int t = threadIdx.x, row = blockIdx.y;
    const int base = blockIdx.x * 2048 + t * 8;
    const int* dg = deg + (size_t)row * SCN + base;
    int v[8];
    #pragma unroll
    for (int j = 0; j < 8; ++j) v[j] = dg[j];
    int tot = 0;
    #pragma unroll
    for (int j = 0; j < 8; ++j) tot += v[j];
    ls[t] = tot;
    __syncthreads();
    #pragma unroll
    for (int d = 1; d < 256; d <<= 1) {
        int tv = (t >= d) ? ls[t - d] : 0;
        __syncthreads();
        ls[t] += tv;
        __syncthreads();
    }
    int run = ls[t] - tot;
    int* op = off + (size_t)row * SCN + base;
    #pragma unroll
    for (int j = 0; j < 8; ++j) { op[j] = run; run += v[j]; }
    if (t == 255) bsum[row * 64 + blockIdx.x] = ls[255];
}

__global__ __launch_bounds__(256) void scanB(int* __restrict__ bsum)
{
    if (threadIdx.x < 2) {
        int row = threadIdx.x, c = 0;
        for (int i = 0; i < NB; ++i) {
            int tv = bsum[row * 64 + i];
            bsum[row * 64 + i] = c;
            c += tv;
        }
    }
}

__global__ __launch_bounds__(256) void scanC(
    int* __restrict__ off, const int* __restrict__ bsum, int* __restrict__ cur)
{
    const int t = threadIdx.x, row = blockIdx.y;
    const int base = blockIdx.x * 2048 + t * 8;
    const int add = bsum[row * 64 + blockIdx.x];
    int* op = off + (size_t)row * SCN + base;
    int* cp = cur + (size_t)row * SCN + base;
    #pragma unroll
    for (int j = 0; j < 8; ++j) {
        int v = op[j] + add;
        op[j] = v;
        cp[j] = v;
    }
}

__global__ __launch_bounds__(256) void fill_adj(
    const int* __restrict__ src, const int* __restrict__ dst,
    int* __restrict__ cur, int* __restrict__ adj)
{
    int e = blockIdx.x * 256 + threadIdx.x;
    if (e >= EE) return;
    int s = src[e], d = dst[e];
    int pd = atomicAdd(&cur[d], 1);
    adj[pd] = s;
    int ps = atomicAdd(&cur[SCN + s], 1);
    adj[EE + ps] = d;
}

// ---------------- aggregation (no atomics, vectorized aligned gathers) ------
__global__ __launch_bounds__(256) void aggregate(
    const int* __restrict__ off, const int* __restrict__ adj,
    const unsigned short* __restrict__ P,
    const float* __restrict__ br, const float* __restrict__ bc,
    unsigned short* __restrict__ RC)
{
    const int n    = blockIdx.x * 4 + (threadIdx.x >> 6);
    const int dir  = blockIdx.y;
    const int lane = threadIdx.x & 63;
    const int c    = lane * 4;             // col base within 150-wide region

    if (lane < 10)
        RC[(size_t)n * KP + (dir ? 310 : 150) + lane] = 0;
    if (c >= 152) return;

    const int* offp = off + (size_t)dir * SCN;
    const int* adjp = adj + (size_t)dir * EE;
    const float* bias = dir ? bc : br;
    const unsigned short* own = P + (size_t)n * NPJ + (dir ? P_AC : P_AR);
    const int poff = dir ? P_BC : P_BR;
    const unsigned short* Pg = P + poff;

    const bool g0 = (c + 0) < 150, g1 = (c + 1) < 150;
    const bool g2 = (c + 2) < 150, g3 = (c + 3) < 150;

    bf16x4 ow = *((const bf16x4*)&own[c]);
    float o0 = bf2f((unsigned short)ow[0]) + (g0 ? bias[c + 0] : 0.f);
    float o1 = bf2f((unsigned short)ow[1]) + (g1 ? bias[c + 1] : 0.f);
    float o2 = bf2f((unsigned short)ow[2]) + (g2 ? bias[c + 2] : 0.f);
    float o3 = bf2f((unsigned short)ow[3]) + (g3 ? bias[c + 3] : 0.f);

    float s0 = 0.f, s1 = 0.f, s2 = 0.f, s3 = 0.f;
    int beg = offp[n], end = offp[n + 1];
    if (beg < end) {
        int a = adjp[beg];
        for (int i = beg; i < end; ++i) {
            int anext = (i + 1 < end) ? adjp[i + 1] : 0;
            const unsigned short* pp = Pg + (unsigned)a * (unsigned)NPJ;
            bf16x4 pv = *((const bf16x4*)&pp[c]);
            s0 += gelu_exact(o0 + bf2f((unsigned short)pv[0]));
            s1 += gelu_exact(o1 + bf2f((unsigned short)pv[1]));
            s2 += gelu_exact(o2 + bf2f((unsigned short)pv[2]));
            s3 += gelu_exact(o3 + bf2f((unsigned short)pv[3]));
            a = anext;
        }
    }
    unsigned short* outrow = RC + (size_t)n * KP + (dir ? RC_C : RC_R);
    if (c + 4 <= 150) {
        bf16x4 o;
        o[0] = (short)f2bf(s0); o[1] = (short)f2bf(s1);
        o[2] = (short)f2bf(s2); o[3] = (short)f2bf(s3);
        *((bf16x4*)&outrow[c]) = o;
    } else {
        if (g0) outrow[c + 0] = f2bf(s0);
        if (g1) outrow[c + 1] = f2bf(s1);
    }
}

// -------- 8-wave GEMM (R17 machinery, 512 threads): tile 128x128 -------------
// Wave-tile 64x32: h=wid>>2 row-half, cg=wid&3 col-group. Per wave/step:
// 1 global_load_lds + 4 ds_read + 8 MFMA; vmcnt 2/1/0; 1 barrier/step.
// Ring 32KB (4 x 128x32 bf16); per-wave 4.6KB bounce (stride 36, conflict-free)
// overlaps ring after drain. LDS 36.9KB.
#define GLOAD16(gp, lp) __builtin_amdgcn_global_load_lds( \
    (const __attribute__((address_space(1))) unsigned int*)(gp), \
    (__attribute__((address_space(3))) unsigned int*)(lp), 16, 0, 0)

// MODE 0: P[row*NPJ+col] = bf16(acc)
// MODE 1: nv = vbf_old + gelu(acc + bias[col]); last? out=fp32(nv) : vbf=bf16(nv)
template<int MODE>
__global__ __launch_bounds__(512) void gemm_lo(
    const unsigned short* __restrict__ Ab,
    const unsigned short* __restrict__ Bt,
    unsigned short* __restrict__ P,
    float* __restrict__ outv, unsigned short* __restrict__ vbf,
    const float* __restrict__ bias, int last)
{
    __shared__ unsigned short smem[18432];         // 36864 B
    unsigned short* Alds = smem;                   // ring: 4 x 4096 shorts (32KB)

    const int tid  = threadIdx.x;
    const int lane = tid & 63;
    const int wid  = tid >> 6;                     // 0..7
    const int h    = wid >> 2;                     // row half
    const int cg   = wid & 3;                      // col group

    // bijective XCD swizzle (m204)
    const int gx   = gridDim.x;
    const int nwg  = gx * gridDim.y;
    const int flat = blockIdx.y * gx + blockIdx.x;
    const int q = nwg >> 3, r = nwg & 7;
    const int xcd = flat & 7, off = flat >> 3;
    const int lid = (xcd < r ? xcd * (q + 1) : r * (q + 1) + (xcd - r) * q) + off;
    const int brow = (lid / gx) * 128;
    const int bcol = (lid % gx) * 128;
    const int wn   = cg * 32;

    f32x4 acc[4][2];
    #pragma unroll
    for (int i = 0; i < 4; ++i)
        #pragma unroll
        for (int j = 0; j < 2; ++j)
            #pragma unroll
            for (int rr = 0; rr < 4; ++rr) acc[i][j][rr] = 0.f;

    // ---- B panel fragments (wave's 32 cols, all K) ----
    bf16x8 bfr[NTK][2];
    const unsigned short* Bb =
        Bt + (size_t)(bcol + wn + (lane & 15)) * KP + (lane >> 4) * 8;
    #pragma unroll
    for (int t = 0; t < NTK; ++t) {
        bfr[t][0] = *((const bf16x8*)(Bb + t * 32));
        bfr[t][1] = *((const bf16x8*)(Bb + (size_t)16 * KP + t * 32));
    }

    // per-thread A staging coords (chunk = tid; 128 rows x 4 chunks of 16B)
    const int arow = tid >> 2;
    const int ac   = (tid & 3) ^ ((arow >> 1) & 3);   // swizzled source chunk
    const unsigned short* asrc = Ab + (size_t)(brow + arow) * KP + ac * 8;

    // prologue: stage A tiles 0,1,2 (1 vmem op per wave per tile)
    #pragma unroll
    for (int t = 0; t < 3; ++t)
        GLOAD16(asrc + t * 32, Alds + t * 4096 + wid * 512);

    #pragma unroll
    for (int t = 0; t < NTK; ++t) {
        unsigned short* Alc = Alds + (t & 3) * 4096;
        if (t + 2 < NTK) {
            asm volatile("s_waitcnt vmcnt(2)" ::: "memory");
        } else if (t + 1 < NTK) {
            asm volatile("s_waitcnt vmcnt(1)" ::: "memory");
        } else {
            asm volatile("s_waitcnt vmcnt(0)" ::: "memory");
        }
        __builtin_amdgcn_s_barrier();
        if (t + 3 < NTK)
            GLOAD16(asrc + (t + 3) * 32, Alds + ((t + 3) & 3) * 4096 + wid * 512);

        bf16x8 af[4];
        #pragma unroll
        for (int mi = 0; mi < 4; ++mi) {
            int row = h * 64 + mi * 16 + (lane & 15);
            af[mi] = *((const bf16x8*)&Alc[row * 32 + (((lane >> 4) ^ ((row >> 1) & 3)) * 8)]);
        }
        __builtin_amdgcn_s_setprio(1);
        #pragma unroll
        for (int mi = 0; mi < 4; ++mi)
            #pragma unroll
            for (int nj = 0; nj < 2; ++nj)
                acc[mi][nj] = __builtin_amdgcn_mfma_f32_16x16x32_bf16(
                    af[mi], bfr[t][nj], acc[mi][nj], 0, 0, 0);
        __builtin_amdgcn_s_setprio(0);
    }
    __syncthreads();   // all staging drained; ring reusable as per-wave bounces

    if (MODE == 0) {
        // per-wave bf16 bounce [64][36] = 2304 shorts at smem + wid*2304
        unsigned short* sb = &smem[wid * 2304];
        #pragma unroll
        for (int mi = 0; mi < 4; ++mi)
            #pragma unroll
            for (int nj = 0; nj < 2; ++nj)
                #pragma unroll
                for (int rr = 0; rr < 4; ++rr) {
                    int row = mi * 16 + ((lane >> 4) << 2) + rr;
                    sb[row * 36 + nj * 16 + (lane & 15)] = f2bf(acc[mi][nj][rr]);
                }
        #pragma unroll
        for (int i = 0; i < 4; ++i) {
            int row = i * 16 + (lane >> 2);
            bf16x8 v = *((const bf16x8*)&sb[row * 36 + (lane & 3) * 8]);
            *((bf16x8*)&P[(size_t)(brow + h * 64 + row) * NPJ + bcol + wn + (lane & 3) * 8]) = v;
        }
    } else {
        // per-wave fp32 bounce [32][36] = 4608B, two 32-row passes
        float* fb = (float*)&smem[wid * 2304];
        const int gc = bcol + wn + (lane & 7) * 4;
        #pragma unroll
        for (int h2 = 0; h2 < 2; ++h2) {
            #pragma unroll
            for (int mi2 = 0; mi2 < 2; ++mi2)
                #pragma unroll
                for (int nj = 0; nj < 2; ++nj)
                    #pragma unroll
                    for (int rr = 0; rr < 4; ++rr) {
                        int row32 = mi2 * 16 + ((lane >> 4) << 2) + rr;
                        fb[row32 * 36 + nj * 16 + (lane & 15)] = acc[h2 * 2 + mi2][nj][rr];
                    }
            #pragma unroll
            for (int i = 0; i < 4; ++i) {
                int row32 = i * 8 + (lane >> 3);
                int grow = brow + h * 64 + h2 * 32 + row32;
                float4 vv = *((const float4*)&fb[row32 * 36 + (lane & 7) * 4]);
                if (grow < NND) {
                    if (gc + 4 <= DD) {
                        float4 bv = *((const float4*)&bias[gc]);
                        bf16x4 old = *((const bf16x4*)&vbf[(size_t)grow * KP + gc]);
                        float4 nv;
                        nv.x = bf2f((unsigned short)old[0]) + gelu_exact(vv.x + bv.x);
                        nv.y = bf2f((unsigned short)old[1]) + gelu_exact(vv.y + bv.y);
                        nv.z = bf2f((unsigned short)old[2]) + gelu_exact(vv.z + bv.z);
                        nv.w = bf2f((unsigned short)old[3]) + gelu_exact(vv.w + bv.w);
                        if (last) {
                            *((float4*)&outv[(size_t)grow * DD + gc]) = nv;
                        } else {
                            bf16x4 o;
                            o[0] = (short)f2bf(nv.x); o[1] = (short)f2bf(nv.y);
                            o[2] = (short)f2bf(nv.z); o[3] = (short)f2bf(nv.w);
                            *((bf16x4*)&vbf[(size_t)grow * KP + gc]) = o;
                        }
                    } else {
                        #pragma unroll
                        for (int j = 0; j < 4; ++j) {
                            int ccc = gc + j;
                            if (ccc < DD) {
                                float vj = (j == 0) ? vv.x : (j == 1) ? vv.y
                                         : (j == 2) ? vv.z : vv.w;
                                size_t vidx = (size_t)grow * KP + ccc;
                                float nv = bf2f(vbf[vidx]) + gelu_exact(vj + bias[ccc]);
                                if (last) outv[(size_t)grow * DD + ccc] = nv;
                                else      vbf[vidx] = f2bf(nv);
                            }
                        }
                    }
                }
            }
        }
    }
}

extern "C" void kernel_launch(void* const* d_in, const int* in_sizes, int n_in,
                              void* d_out, int out_size, void* d_ws, size_t ws_size,
                              hipStream_t stream) {
    const float* x  = (const float*)d_in[0];
    const int*   ei = (const int*)  d_in[1];
    const float* Wr = (const float*)d_in[2];
    const float* br = (const float*)d_in[3];
    const float* Wc = (const float*)d_in[4];
    const float* bc = (const float*)d_in[5];
    const float* Wa = (const float*)d_in[6];
    const float* ba = (const float*)d_in[7];
    float* out = (float*)d_out;

    const size_t P_elems   = (size_t)MPAD * NPJ;   // bf16
    const size_t RC_elems  = (size_t)MPAD * KP;    // bf16
    const size_t V_elems   = (size_t)MPAD * KP;    // bf16
    const size_t Bt_elems  = (size_t)LL * NPJ * KP;
    const size_t Wat_elems = (size_t)NUP * KP;

    unsigned short* P   = (unsigned short*)d_ws;
    unsigned short* RC  = P + P_elems;
    unsigned short* vbf = RC + RC_elems;
    unsigned short* Bt  = vbf + V_elems;
    unsigned short* Wat = Bt + Bt_elems;
    int* deg  = (int*)(Wat + Wat_elems);
    int* off  = deg + 2 * SCN;
    int* curp = off + 2 * SCN;
    int* adj  = curp + 2 * SCN;
    int* bsum = adj + 2 * EE;
    const size_t need = (char*)(bsum + 128) - (char*)d_ws;
    if (ws_size < need) return;  // visible fail (output stays poisoned)

    pack_w<<<2880, 256, 0, stream>>>(Wr, Wc, Wa, Bt, Wat);
    init_vbf<<<(int)((V_elems / 8 + 255) / 256), 256, 0, stream>>>(x, vbf);

    const int* src = ei;
    const int* dst = ei + EE;

    hipMemsetAsync(deg, 0, 2 * SCN * sizeof(int), stream);
    hist_deg<<<(EE + 255) / 256, 256, 0, stream>>>(src, dst, deg);
    scanA<<<dim3(NB, 2), 256, 0, stream>>>(deg, off, bsum);
    scanB<<<1, 256, 0, stream>>>(bsum);
    scanC<<<dim3(NB, 2), 256, 0, stream>>>(off, bsum, curp);
    fill_adj<<<(EE + 255) / 256, 256, 0, stream>>>(src, dst, curp, adj);

    dim3 gproj(NPJ / 128, MPAD / 128);   // (5, 782)
    dim3 gupd (NUP / 128, MPAD / 128);   // (3, 782)
    dim3 gagg (MPAD / 4, 2);

    for (int l = 0; l < LL; ++l) {
        gemm_lo<0><<<gproj, 512, 0, stream>>>(
            vbf, Bt + (size_t)l * NPJ * KP, P, nullptr, nullptr, nullptr, 0);
        aggregate<<<gagg, 256, 0, stream>>>(
            off, adj, P, br + (size_t)l * HH, bc + (size_t)l * HH, RC);
        gemm_lo<1><<<gupd, 512, 0, stream>>>(
            RC, Wat, nullptr, out, vbf, ba, (l == LL - 1) ? 1 : 0);
    }
}

// Round 19
// 852.856 us; speedup vs baseline: 1.2212x; 1.2212x over previous
//
#include <hip/hip_runtime.h>
#include <hip/hip_bf16.h>
#include <math.h>

#define NND 100000   // nodes
#define EE  200000   // edges
#define LL  3        // layers
#define DD  300      // node dim
#define HH  150      // per-direction message dim

#define MPAD 100096  // 1564*64
#define KP   320     // K padded (multiple of 32)
#define NPJ  640     // proj N padded
#define NUP  384     // update N padded
#define NTK  (KP / 32)

#define NB   49          // scan blocks (2048 elems each)
#define SCN  (NB * 2048) // 100352 >= MPAD+1

// P column layout (all 8B-aligned region starts, pads zero):
//  Br @ 0..149 | Bc @ 152..301 | Ar @ 304..453 | Ac @ 456..605
#define P_BR 0
#define P_BC 152
#define P_AR 304
#define P_AC 456
// RC column layout: r @ 0..149, pad, c @ 160..309, pad
#define RC_R 0
#define RC_C 160

typedef __attribute__((ext_vector_type(8))) short bf16x8;
typedef __attribute__((ext_vector_type(4))) short bf16x4;
typedef __attribute__((ext_vector_type(4))) float f32x4;

// fast GELU (tanh-form): max abs dev from exact-erf GELU ~1e-3.
__device__ __forceinline__ float gelu_exact(float x) {
    float x2 = x * x;
    float y2 = -1.5957691216f * (x + 0.044715f * x2 * x);
    float e  = __expf(y2);
    return x * __builtin_amdgcn_rcpf(1.f + e);
}
__device__ __forceinline__ unsigned short f2bf(float f) {
    union { float fv; unsigned u; } v; v.fv = f;
    unsigned r = v.u + 0x7fff + ((v.u >> 16) & 1);   // RNE (finite inputs)
    return (unsigned short)(r >> 16);
}
__device__ __forceinline__ float bf2f(unsigned short b) {
    union { unsigned u; float fv; } v; v.u = ((unsigned)b) << 16;
    return v.fv;
}

// ---------------- weight packing ----------------
__global__ __launch_bounds__(256) void pack_w(
    const float* __restrict__ Wr, const float* __restrict__ Wc,
    const float* __restrict__ Wa,
    unsigned short* __restrict__ Bt, unsigned short* __restrict__ Wat)
{
    int i = blockIdx.x * 256 + threadIdx.x;
    const int btTotal = LL * NPJ * KP;
    if (i < btTotal) {
        int l = i / (NPJ * KP);
        int rem = i % (NPJ * KP);
        int n = rem / KP;
        int k = rem % KP;
        float v = 0.f;
        if (k < DD) {
            const float* W = nullptr; int krow = k, j = -1;
            if (n >= P_BR && n < P_BR + 150)      { W = Wr; krow = 300 + k; j = n - P_BR; }
            else if (n >= P_BC && n < P_BC + 150) { W = Wc; krow = 300 + k; j = n - P_BC; }
            else if (n >= P_AR && n < P_AR + 150) { W = Wr; krow = k;       j = n - P_AR; }
            else if (n >= P_AC && n < P_AC + 150) { W = Wc; krow = k;       j = n - P_AC; }
            if (j >= 0)
                v = W[(size_t)l * 600 * 150 + (size_t)krow * 150 + j];
        }
        Bt[i] = f2bf(v);
    } else {
        int i2 = i - btTotal;
        if (i2 < NUP * KP) {
            int n = i2 / KP, k = i2 % KP;
            int kk = -1;
            if (k < 150)                 kk = k;          // r rows of Wa
            else if (k >= 160 && k < 310) kk = k - 10;    // c rows of Wa
            float v = (n < DD && kk >= 0) ? Wa[(size_t)kk * DD + n] : 0.f;
            Wat[i2] = f2bf(v);
        }
    }
}

// vbf[MPAD][KP] = bf16(x), zero pads
__global__ __launch_bounds__(256) void init_vbf(
    const float* __restrict__ x, unsigned short* __restrict__ vbf)
{
    int idx = blockIdx.x * 256 + threadIdx.x;       // chunk of 8
    int row = idx / (KP / 8);
    int gk  = (idx % (KP / 8)) * 8;
    if (row >= MPAD) return;
    unsigned short tmp[8];
    if (row < NND && gk < DD) {
        if (gk + 8 <= DD) {
            const float4* p = (const float4*)(x + (size_t)row * DD + gk);
            float4 f0 = p[0], f1 = p[1];
            tmp[0] = f2bf(f0.x); tmp[1] = f2bf(f0.y);
            tmp[2] = f2bf(f0.z); tmp[3] = f2bf(f0.w);
            tmp[4] = f2bf(f1.x); tmp[5] = f2bf(f1.y);
            tmp[6] = f2bf(f1.z); tmp[7] = f2bf(f1.w);
        } else {
            #pragma unroll
            for (int j = 0; j < 8; ++j)
                tmp[j] = (gk + j < DD) ? f2bf(x[(size_t)row * DD + gk + j]) : 0;
        }
    } else {
        #pragma unroll
        for (int j = 0; j < 8; ++j) tmp[j] = 0;
    }
    *((bf16x8*)&vbf[(size_t)row * KP + gk]) = *((bf16x8*)tmp);
}

// ---------------- CSR build ----------------
__global__ __launch_bounds__(256) void hist_deg(
    const int* __restrict__ src, const int* __restrict__ dst,
    int* __restrict__ deg)
{
    int e = blockIdx.x * 256 + threadIdx.x;
    if (e >= EE) return;
    atomicAdd(&deg[dst[e]], 1);
    atomicAdd(&deg[SCN + src[e]], 1);
}

__global__ __launch_bounds__(256) void scanA(
    const int* __restrict__ deg, int* __restrict__ off, int* __restrict__ bsum)
{
    __shared__ int ls[256];
    const int t = threadIdx.x, row = blockIdx.y;
    const int base = blockIdx.x * 2048 + t * 8;
    const int* dg = deg + (size_t)row * SCN + base;
    int v[8];
    #pragma unroll
    for (int j = 0; j < 8; ++j) v[j] = dg[j];
    int tot = 0;
    #pragma unroll
    for (int j = 0; j < 8; ++j) tot += v[j];
    ls[t] = tot;
    __syncthreads();
    #pragma unroll
    for (int d = 1; d < 256; d <<= 1) {
        int tv = (t >= d) ? ls[t - d] : 0;
        __syncthreads();
        ls[t] += tv;
        __syncthreads();
    }
    int run = ls[t] - tot;
    int* op = off + (size_t)row * SCN + base;
    #pragma unroll
    for (int j = 0; j < 8; ++j) { op[j] = run; run += v[j]; }
    if (t == 255) bsum[row * 64 + blockIdx.x] = ls[255];
}

__global__ __launch_bounds__(256) void scanB(int* __restrict__ bsum)
{
    if (threadIdx.x < 2) {
        int row = threadIdx.x, c = 0;
        for (int i = 0; i < NB; ++i) {
            int tv = bsum[row * 64 + i];
            bsum[row * 64 + i] = c;
            c += tv;
        }
    }
}

__global__ __launch_bounds__(256) void scanC(
    int* __restrict__ off, const int* __restrict__ bsum, int* __restrict__ cur)
{
    const int t = threadIdx.x, row = blockIdx.y;
    const int base = blockIdx.x * 2048 + t * 8;
    const int add = bsum[row * 64 + blockIdx.x];
    int* op = off + (size_t)row * SCN + base;
    int* cp = cur + (size_t)row * SCN + base;
    #pragma unroll
    for (int j = 0; j < 8; ++j) {
        int v = op[j] + add;
        op[j] = v;
        cp[j] = v;
    }
}

__global__ __launch_bounds__(256) void fill_adj(
    const int* __restrict__ src, const int* __restrict__ dst,
    int* __restrict__ cur, int* __restrict__ adj)
{
    int e = blockIdx.x * 256 + threadIdx.x;
    if (e >= EE) return;
    int s = src[e], d = dst[e];
    int pd = atomicAdd(&cur[d], 1);
    adj[pd] = s;
    int ps = atomicAdd(&cur[SCN + s], 1);
    adj[EE + ps] = d;
}

// ---------------- aggregation (no atomics, vectorized aligned gathers) ------
__global__ __launch_bounds__(256) void aggregate(
    const int* __restrict__ off, const int* __restrict__ adj,
    const unsigned short* __restrict__ P,
    const float* __restrict__ br, const float* __restrict__ bc,
    unsigned short* __restrict__ RC)
{
    const int n    = blockIdx.x * 4 + (threadIdx.x >> 6);
    const int dir  = blockIdx.y;
    const int lane = threadIdx.x & 63;
    const int c    = lane * 4;             // col base within 150-wide region

    if (lane < 10)
        RC[(size_t)n * KP + (dir ? 310 : 150) + lane] = 0;
    if (c >= 152) return;

    const int* offp = off + (size_t)dir * SCN;
    const int* adjp = adj + (size_t)dir * EE;
    const float* bias = dir ? bc : br;
    const unsigned short* own = P + (size_t)n * NPJ + (dir ? P_AC : P_AR);
    const int poff = dir ? P_BC : P_BR;
    const unsigned short* Pg = P + poff;

    const bool g0 = (c + 0) < 150, g1 = (c + 1) < 150;
    const bool g2 = (c + 2) < 150, g3 = (c + 3) < 150;

    bf16x4 ow = *((const bf16x4*)&own[c]);
    float o0 = bf2f((unsigned short)ow[0]) + (g0 ? bias[c + 0] : 0.f);
    float o1 = bf2f((unsigned short)ow[1]) + (g1 ? bias[c + 1] : 0.f);
    float o2 = bf2f((unsigned short)ow[2]) + (g2 ? bias[c + 2] : 0.f);
    float o3 = bf2f((unsigned short)ow[3]) + (g3 ? bias[c + 3] : 0.f);

    float s0 = 0.f, s1 = 0.f, s2 = 0.f, s3 = 0.f;
    int beg = offp[n], end = offp[n + 1];
    if (beg < end) {
        int a = adjp[beg];
        for (int i = beg; i < end; ++i) {
            int anext = (i + 1 < end) ? adjp[i + 1] : 0;
            const unsigned short* pp = Pg + (unsigned)a * (unsigned)NPJ;
            bf16x4 pv = *((const bf16x4*)&pp[c]);
            s0 += gelu_exact(o0 + bf2f((unsigned short)pv[0]));
            s1 += gelu_exact(o1 + bf2f((unsigned short)pv[1]));
            s2 += gelu_exact(o2 + bf2f((unsigned short)pv[2]));
            s3 += gelu_exact(o3 + bf2f((unsigned short)pv[3]));
            a = anext;
        }
    }
    unsigned short* outrow = RC + (size_t)n * KP + (dir ? RC_C : RC_R);
    if (c + 4 <= 150) {
        bf16x4 o;
        o[0] = (short)f2bf(s0); o[1] = (short)f2bf(s1);
        o[2] = (short)f2bf(s2); o[3] = (short)f2bf(s3);
        *((bf16x4*)&outrow[c]) = o;
    } else {
        if (g0) outrow[c + 0] = f2bf(s0);
        if (g1) outrow[c + 1] = f2bf(s1);
    }
}

// -------- low-LDS GEMM (R17 + depth-4 ring + stride-36 bounce) ---------------
// Tile 64x128, 4 waves; 1 gload_lds/wave/step; 6-buffer ring (24KB), steady
// vmcnt(4); 1 barrier/step; per-wave 4.6KB bounce overlapping ring after drain.
#define GLOAD16(gp, lp) __builtin_amdgcn_global_load_lds( \
    (const __attribute__((address_space(1))) unsigned int*)(gp), \
    (__attribute__((address_space(3))) unsigned int*)(lp), 16, 0, 0)

// MODE 0: P[row*NPJ+col] = bf16(acc)
// MODE 1: nv = vbf_old + gelu(acc + bias[col]); last? out=fp32(nv) : vbf=bf16(nv)
template<int MODE>
__global__ __launch_bounds__(256) void gemm_lo(
    const unsigned short* __restrict__ Ab,
    const unsigned short* __restrict__ Bt,
    unsigned short* __restrict__ P,
    float* __restrict__ outv, unsigned short* __restrict__ vbf,
    const float* __restrict__ bias, int last)
{
    __shared__ unsigned short smem[12288];         // 24576 B
    unsigned short* Alds = smem;                   // ring: 6 x 2048 shorts

    const int tid  = threadIdx.x;
    const int lane = tid & 63;
    const int wid  = tid >> 6;

    // bijective XCD swizzle (m204)
    const int gx   = gridDim.x;
    const int nwg  = gx * gridDim.y;
    const int flat = blockIdx.y * gx + blockIdx.x;
    const int q = nwg >> 3, r = nwg & 7;
    const int xcd = flat & 7, off = flat >> 3;
    const int lid = (xcd < r ? xcd * (q + 1) : r * (q + 1) + (xcd - r) * q) + off;
    const int brow = (lid / gx) * 64;
    const int bcol = (lid % gx) * 128;
    const int wn   = wid * 32;

    f32x4 acc[4][2];
    #pragma unroll
    for (int i = 0; i < 4; ++i)
        #pragma unroll
        for (int j = 0; j < 2; ++j)
            #pragma unroll
            for (int rr = 0; rr < 4; ++rr) acc[i][j][rr] = 0.f;

    // ---- B panel fragments ----
    bf16x8 bfr[NTK][2];
    const unsigned short* Bb =
        Bt + (size_t)(bcol + wn + (lane & 15)) * KP + (lane >> 4) * 8;
    #pragma unroll
    for (int t = 0; t < NTK; ++t) {
        bfr[t][0] = *((const bf16x8*)(Bb + t * 32));
        bfr[t][1] = *((const bf16x8*)(Bb + (size_t)16 * KP + t * 32));
    }

    // per-thread A staging coords (chunk = tid; 64 rows x 4 chunks of 16B)
    const int arow = tid >> 2;
    const int ac   = (tid & 3) ^ ((arow >> 1) & 3);   // swizzled source chunk
    const unsigned short* asrc = Ab + (size_t)(brow + arow) * KP + ac * 8;

    // prologue: stage A tiles 0..4 (1 vmem op per wave per tile)
    #pragma unroll
    for (int t = 0; t < 5; ++t)
        GLOAD16(asrc + t * 32, Alds + (t % 6) * 2048 + wid * 512);

    #pragma unroll
    for (int t = 0; t < NTK; ++t) {
        unsigned short* Alc = Alds + (t % 6) * 2048;
        if (t <= NTK - 5) {
            asm volatile("s_waitcnt vmcnt(4)" ::: "memory");
        } else if (t == NTK - 4) {
            asm volatile("s_waitcnt vmcnt(3)" ::: "memory");
        } else if (t == NTK - 3) {
            asm volatile("s_waitcnt vmcnt(2)" ::: "memory");
        } else if (t == NTK - 2) {
            asm volatile("s_waitcnt vmcnt(1)" ::: "memory");
        } else {
            asm volatile("s_waitcnt vmcnt(0)" ::: "memory");
        }
        __builtin_amdgcn_s_barrier();
        // stage t+5 into buf (t+5)%6 = (t-1)%6: safe, barrier implies iter t-1
        // reads completed on all waves
        if (t + 5 < NTK)
            GLOAD16(asrc + (t + 5) * 32, Alds + ((t + 5) % 6) * 2048 + wid * 512);

        bf16x8 af[4];
        #pragma unroll
        for (int mi = 0; mi < 4; ++mi) {
            int row = mi * 16 + (lane & 15);
            af[mi] = *((const bf16x8*)&Alc[row * 32 + (((lane >> 4) ^ ((row >> 1) & 3)) * 8)]);
        }
        __builtin_amdgcn_s_setprio(1);
        #pragma unroll
        for (int mi = 0; mi < 4; ++mi)
            #pragma unroll
            for (int nj = 0; nj < 2; ++nj)
                acc[mi][nj] = __builtin_amdgcn_mfma_f32_16x16x32_bf16(
                    af[mi], bfr[t][nj], acc[mi][nj], 0, 0, 0);
        __builtin_amdgcn_s_setprio(0);
    }
    __syncthreads();   // all staging drained; ring reusable as per-wave bounces

    if (MODE == 0) {
        // per-wave bf16 bounce [64][36] = 2304 shorts at smem + wid*2304
        unsigned short* sb = &smem[wid * 2304];
        #pragma unroll
        for (int mi = 0; mi < 4; ++mi)
            #pragma unroll
            for (int nj = 0; nj < 2; ++nj)
                #pragma unroll
                for (int rr = 0; rr < 4; ++rr) {
                    int row = mi * 16 + ((lane >> 4) << 2) + rr;
                    sb[row * 36 + nj * 16 + (lane & 15)] = f2bf(acc[mi][nj][rr]);
                }
        #pragma unroll
        for (int i = 0; i < 4; ++i) {
            int row = i * 16 + (lane >> 2);
            bf16x8 v = *((const bf16x8*)&sb[row * 36 + (lane & 3) * 8]);
            *((bf16x8*)&P[(size_t)(brow + row) * NPJ + bcol + wn + (lane & 3) * 8]) = v;
        }
    } else {
        // per-wave fp32 bounce [32][36] = 4608B, two 32-row passes
        float* fb = (float*)&smem[wid * 2304];
        const int gc = bcol + wn + (lane & 7) * 4;
        #pragma unroll
        for (int h = 0; h < 2; ++h) {
            #pragma unroll
            for (int mi2 = 0; mi2 < 2; ++mi2)
                #pragma unroll
                for (int nj = 0; nj < 2; ++nj)
                    #pragma unroll
                    for (int rr = 0; rr < 4; ++rr) {
                        int row32 = mi2 * 16 + ((lane >> 4) << 2) + rr;
                        fb[row32 * 36 + nj * 16 + (lane & 15)] = acc[h * 2 + mi2][nj][rr];
                    }
            #pragma unroll
            for (int i = 0; i < 4; ++i) {
                int row32 = i * 8 + (lane >> 3);
                int grow = brow + h * 32 + row32;
                float4 vv = *((const float4*)&fb[row32 * 36 + (lane & 7) * 4]);
                if (grow < NND) {
                    if (gc + 4 <= DD) {
                        float4 bv = *((const float4*)&bias[gc]);
                        bf16x4 old = *((const bf16x4*)&vbf[(size_t)grow * KP + gc]);
                        float4 nv;
                        nv.x = bf2f((unsigned short)old[0]) + gelu_exact(vv.x + bv.x);
                        nv.y = bf2f((unsigned short)old[1]) + gelu_exact(vv.y + bv.y);
                        nv.z = bf2f((unsigned short)old[2]) + gelu_exact(vv.z + bv.z);
                        nv.w = bf2f((unsigned short)old[3]) + gelu_exact(vv.w + bv.w);
                        if (last) {
                            *((float4*)&outv[(size_t)grow * DD + gc]) = nv;
                        } else {
                            bf16x4 o;
                            o[0] = (short)f2bf(nv.x); o[1] = (short)f2bf(nv.y);
                            o[2] = (short)f2bf(nv.z); o[3] = (short)f2bf(nv.w);
                            *((bf16x4*)&vbf[(size_t)grow * KP + gc]) = o;
                        }
                    } else {
                        #pragma unroll
                        for (int j = 0; j < 4; ++j) {
                            int ccc = gc + j;
                            if (ccc < DD) {
                                float vj = (j == 0) ? vv.x : (j == 1) ? vv.y
                                         : (j == 2) ? vv.z : vv.w;
                                size_t vidx = (size_t)grow * KP + ccc;
                                float nv = bf2f(vbf[vidx]) + gelu_exact(vj + bias[ccc]);
                                if (last) outv[(size_t)grow * DD + ccc] = nv;
                                else      vbf[vidx] = f2bf(nv);
                            }
                        }
                    }
                }
            }
        }
    }
}

extern "C" void kernel_launch(void* const* d_in, const int* in_sizes, int n_in,
                              void* d_out, int out_size, void* d_ws, size_t ws_size,
                              hipStream_t stream) {
    const float* x  = (const float*)d_in[0];
    const int*   ei = (const int*)  d_in[1];
    const float* Wr = (const float*)d_in[2];
    const float* br = (const float*)d_in[3];
    const float* Wc = (const float*)d_in[4];
    const float* bc = (const float*)d_in[5];
    const float* Wa = (const float*)d_in[6];
    const float* ba = (const float*)d_in[7];
    float* out = (float*)d_out;

    const size_t P_elems   = (size_t)MPAD * NPJ;   // bf16
    const size_t RC_elems  = (size_t)MPAD * KP;    // bf16
    const size_t V_elems   = (size_t)MPAD * KP;    // bf16
    const size_t Bt_elems  = (size_t)LL * NPJ * KP;
    const size_t Wat_elems = (size_t)NUP * KP;

    unsigned short* P   = (unsigned short*)d_ws;
    unsigned short* RC  = P + P_elems;
    unsigned short* vbf = RC + RC_elems;
    unsigned short* Bt  = vbf + V_elems;
    unsigned short* Wat = Bt + Bt_elems;
    int* deg  = (int*)(Wat + Wat_elems);
    int* off  = deg + 2 * SCN;
    int* curp = off + 2 * SCN;
    int* adj  = curp + 2 * SCN;
    int* bsum = adj + 2 * EE;
    const size_t need = (char*)(bsum + 128) - (char*)d_ws;
    if (ws_size < need) return;  // visible fail (output stays poisoned)

    pack_w<<<2880, 256, 0, stream>>>(Wr, Wc, Wa, Bt, Wat);
    init_vbf<<<(int)((V_elems / 8 + 255) / 256), 256, 0, stream>>>(x, vbf);

    const int* src = ei;
    const int* dst = ei + EE;

    hipMemsetAsync(deg, 0, 2 * SCN * sizeof(int), stream);
    hist_deg<<<(EE + 255) / 256, 256, 0, stream>>>(src, dst, deg);
    scanA<<<dim3(NB, 2), 256, 0, stream>>>(deg, off, bsum);
    scanB<<<1, 256, 0, stream>>>(bsum);
    scanC<<<dim3(NB, 2), 256, 0, stream>>>(off, bsum, curp);
    fill_adj<<<(EE + 255) / 256, 256, 0, stream>>>(src, dst, curp, adj);

    dim3 gproj(NPJ / 128, MPAD / 64);   // (5, 1564)
    dim3 gupd (NUP / 128, MPAD / 64);   // (3, 1564)
    dim3 gagg (MPAD / 4, 2);

    for (int l = 0; l < LL; ++l) {
        gemm_lo<0><<<gproj, 256, 0, stream>>>(
            vbf, Bt + (size_t)l * NPJ * KP, P, nullptr, nullptr, nullptr, 0);
        aggregate<<<gagg, 256, 0, stream>>>(
            off, adj, P, br + (size_t)l * HH, bc + (size_t)l * HH, RC);
        gemm_lo<1><<<gupd, 256, 0, stream>>>(
            RC, Wat, nullptr, out, vbf, ba, (l == LL - 1) ? 1 : 0);
    }
}

// Round 20
// 852.137 us; speedup vs baseline: 1.2222x; 1.0008x over previous
//
#include <hip/hip_runtime.h>
#include <hip/hip_bf16.h>
#include <math.h>

#define NND 100000   // nodes
#define EE  200000   // edges
#define LL  3        // layers
#define DD  300      // node dim
#define HH  150      // per-direction message dim

#define MPAD 100096  // 1564*64
#define KP   320     // K padded (multiple of 32)
#define NPJ  640     // proj N padded
#define NUP  384     // update N padded
#define NTK  (KP / 32)

#define NB   49          // scan blocks (2048 elems each)
#define SCN  (NB * 2048) // 100352 >= MPAD+1

// P column layout (all 8B-aligned region starts, pads zero):
//  Br @ 0..149 | Bc @ 152..301 | Ar @ 304..453 | Ac @ 456..605
#define P_BR 0
#define P_BC 152
#define P_AR 304
#define P_AC 456
// RC column layout: r @ 0..149, pad, c @ 160..309, pad
#define RC_R 0
#define RC_C 160

typedef __attribute__((ext_vector_type(8))) short bf16x8;
typedef __attribute__((ext_vector_type(4))) short bf16x4;
typedef __attribute__((ext_vector_type(4))) float f32x4;

// fast GELU (tanh-form): max abs dev from exact-erf GELU ~1e-3.
__device__ __forceinline__ float gelu_exact(float x) {
    float x2 = x * x;
    float y2 = -1.5957691216f * (x + 0.044715f * x2 * x);
    float e  = __expf(y2);
    return x * __builtin_amdgcn_rcpf(1.f + e);
}
__device__ __forceinline__ unsigned short f2bf(float f) {
    union { float fv; unsigned u; } v; v.fv = f;
    unsigned r = v.u + 0x7fff + ((v.u >> 16) & 1);   // RNE (finite inputs)
    return (unsigned short)(r >> 16);
}
__device__ __forceinline__ float bf2f(unsigned short b) {
    union { unsigned u; float fv; } v; v.u = ((unsigned)b) << 16;
    return v.fv;
}

// ---------------- weight packing ----------------
__global__ __launch_bounds__(256) void pack_w(
    const float* __restrict__ Wr, const float* __restrict__ Wc,
    const float* __restrict__ Wa,
    unsigned short* __restrict__ Bt, unsigned short* __restrict__ Wat)
{
    int i = blockIdx.x * 256 + threadIdx.x;
    const int btTotal = LL * NPJ * KP;
    if (i < btTotal) {
        int l = i / (NPJ * KP);
        int rem = i % (NPJ * KP);
        int n = rem / KP;
        int k = rem % KP;
        float v = 0.f;
        if (k < DD) {
            const float* W = nullptr; int krow = k, j = -1;
            if (n >= P_BR && n < P_BR + 150)      { W = Wr; krow = 300 + k; j = n - P_BR; }
            else if (n >= P_BC && n < P_BC + 150) { W = Wc; krow = 300 + k; j = n - P_BC; }
            else if (n >= P_AR && n < P_AR + 150) { W = Wr; krow = k;       j = n - P_AR; }
            else if (n >= P_AC && n < P_AC + 150) { W = Wc; krow = k;       j = n - P_AC; }
            if (j >= 0)
                v = W[(size_t)l * 600 * 150 + (size_t)krow * 150 + j];
        }
        Bt[i] = f2bf(v);
    } else {
        int i2 = i - btTotal;
        if (i2 < NUP * KP) {
            int n = i2 / KP, k = i2 % KP;
            int kk = -1;
            if (k < 150)                 kk = k;          // r rows of Wa
            else if (k >= 160 && k < 310) kk = k - 10;    // c rows of Wa
            float v = (n < DD && kk >= 0) ? Wa[(size_t)kk * DD + n] : 0.f;
            Wat[i2] = f2bf(v);
        }
    }
}

// vbf[MPAD][KP] = bf16(x), zero pads
__global__ __launch_bounds__(256) void init_vbf(
    const float* __restrict__ x, unsigned short* __restrict__ vbf)
{
    int idx = blockIdx.x * 256 + threadIdx.x;       // chunk of 8
    int row = idx / (KP / 8);
    int gk  = (idx % (KP / 8)) * 8;
    if (row >= MPAD) return;
    unsigned short tmp[8];
    if (row < NND && gk < DD) {
        if (gk + 8 <= DD) {
            const float4* p = (const float4*)(x + (size_t)row * DD + gk);
            float4 f0 = p[0], f1 = p[1];
            tmp[0] = f2bf(f0.x); tmp[1] = f2bf(f0.y);
            tmp[2] = f2bf(f0.z); tmp[3] = f2bf(f0.w);
            tmp[4] = f2bf(f1.x); tmp[5] = f2bf(f1.y);
            tmp[6] = f2bf(f1.z); tmp[7] = f2bf(f1.w);
        } else {
            #pragma unroll
            for (int j = 0; j < 8; ++j)
                tmp[j] = (gk + j < DD) ? f2bf(x[(size_t)row * DD + gk + j]) : 0;
        }
    } else {
        #pragma unroll
        for (int j = 0; j < 8; ++j) tmp[j] = 0;
    }
    *((bf16x8*)&vbf[(size_t)row * KP + gk]) = *((bf16x8*)tmp);
}

// ---------------- CSR build ----------------
__global__ __launch_bounds__(256) void hist_deg(
    const int* __restrict__ src, const int* __restrict__ dst,
    int* __restrict__ deg)
{
    int e = blockIdx.x * 256 + threadIdx.x;
    if (e >= EE) return;
    atomicAdd(&deg[dst[e]], 1);
    atomicAdd(&deg[SCN + src[e]], 1);
}

__global__ __launch_bounds__(256) void scanA(
    const int* __restrict__ deg, int* __restrict__ off, int* __restrict__ bsum)
{
    __shared__ int ls[256];
    const int t = threadIdx.x, row = blockIdx.y;
    const int base = blockIdx.x * 2048 + t * 8;
    const int* dg = deg + (size_t)row * SCN + base;
    int v[8];
    #pragma unroll
    for (int j = 0; j < 8; ++j) v[j] = dg[j];
    int tot = 0;
    #pragma unroll
    for (int j = 0; j < 8; ++j) tot += v[j];
    ls[t] = tot;
    __syncthreads();
    #pragma unroll
    for (int d = 1; d < 256; d <<= 1) {
        int tv = (t >= d) ? ls[t - d] : 0;
        __syncthreads();
        ls[t] += tv;
        __syncthreads();
    }
    int run = ls[t] - tot;
    int* op = off + (size_t)row * SCN + base;
    #pragma unroll
    for (int j = 0; j < 8; ++j) { op[j] = run; run += v[j]; }
    if (t == 255) bsum[row * 64 + blockIdx.x] = ls[255];
}

__global__ __launch_bounds__(256) void scanB(int* __restrict__ bsum)
{
    if (threadIdx.x < 2) {
        int row = threadIdx.x, c = 0;
        for (int i = 0; i < NB; ++i) {
            int tv = bsum[row * 64 + i];
            bsum[row * 64 + i] = c;
            c += tv;
        }
    }
}

__global__ __launch_bounds__(256) void scanC(
    int* __restrict__ off, const int* __restrict__ bsum, int* __restrict__ cur)
{
    const int t = threadIdx.x, row = blockIdx.y;
    const int base = blockIdx.x * 2048 + t * 8;
    const int add = bsum[row * 64 + blockIdx.x];
    int* op = off + (size_t)row * SCN + base;
    int* cp = cur + (size_t)row * SCN + base;
    #pragma unroll
    for (int j = 0; j < 8; ++j) {
        int v = op[j] + add;
        op[j] = v;
        cp[j] = v;
    }
}

__global__ __launch_bounds__(256) void fill_adj(
    const int* __restrict__ src, const int* __restrict__ dst,
    int* __restrict__ cur, int* __restrict__ adj)
{
    int e = blockIdx.x * 256 + threadIdx.x;
    if (e >= EE) return;
    int s = src[e], d = dst[e];
    int pd = atomicAdd(&cur[d], 1);
    adj[pd] = s;
    int ps = atomicAdd(&cur[SCN + s], 1);
    adj[EE + ps] = d;
}

// ---------------- aggregation (no atomics, vectorized aligned gathers) ------
__global__ __launch_bounds__(256) void aggregate(
    const int* __restrict__ off, const int* __restrict__ adj,
    const unsigned short* __restrict__ P,
    const float* __restrict__ br, const float* __restrict__ bc,
    unsigned short* __restrict__ RC)
{
    const int n    = blockIdx.x * 4 + (threadIdx.x >> 6);
    const int dir  = blockIdx.y;
    const int lane = threadIdx.x & 63;
    const int c    = lane * 4;             // col base within 150-wide region

    if (lane < 10)
        RC[(size_t)n * KP + (dir ? 310 : 150) + lane] = 0;
    if (c >= 152) return;

    const int* offp = off + (size_t)dir * SCN;
    const int* adjp = adj + (size_t)dir * EE;
    const float* bias = dir ? bc : br;
    const unsigned short* own = P + (size_t)n * NPJ + (dir ? P_AC : P_AR);
    const int poff = dir ? P_BC : P_BR;
    const unsigned short* Pg = P + poff;

    const bool g0 = (c + 0) < 150, g1 = (c + 1) < 150;
    const bool g2 = (c + 2) < 150, g3 = (c + 3) < 150;

    bf16x4 ow = *((const bf16x4*)&own[c]);
    float o0 = bf2f((unsigned short)ow[0]) + (g0 ? bias[c + 0] : 0.f);
    float o1 = bf2f((unsigned short)ow[1]) + (g1 ? bias[c + 1] : 0.f);
    float o2 = bf2f((unsigned short)ow[2]) + (g2 ? bias[c + 2] : 0.f);
    float o3 = bf2f((unsigned short)ow[3]) + (g3 ? bias[c + 3] : 0.f);

    float s0 = 0.f, s1 = 0.f, s2 = 0.f, s3 = 0.f;
    int beg = offp[n], end = offp[n + 1];
    if (beg < end) {
        int a = adjp[beg];
        for (int i = beg; i < end; ++i) {
            int anext = (i + 1 < end) ? adjp[i + 1] : 0;
            const unsigned short* pp = Pg + (unsigned)a * (unsigned)NPJ;
            bf16x4 pv = *((const bf16x4*)&pp[c]);
            s0 += gelu_exact(o0 + bf2f((unsigned short)pv[0]));
            s1 += gelu_exact(o1 + bf2f((unsigned short)pv[1]));
            s2 += gelu_exact(o2 + bf2f((unsigned short)pv[2]));
            s3 += gelu_exact(o3 + bf2f((unsigned short)pv[3]));
            a = anext;
        }
    }
    unsigned short* outrow = RC + (size_t)n * KP + (dir ? RC_C : RC_R);
    if (c + 4 <= 150) {
        bf16x4 o;
        o[0] = (short)f2bf(s0); o[1] = (short)f2bf(s1);
        o[2] = (short)f2bf(s2); o[3] = (short)f2bf(s3);
        *((bf16x4*)&outrow[c]) = o;
    } else {
        if (g0) outrow[c + 0] = f2bf(s0);
        if (g1) outrow[c + 1] = f2bf(s1);
    }
}

// -------- low-LDS GEMM (R19 + B pinned in VGPRs via asm ties) ----------------
// Tile 64x128, 4 waves; 1 gload_lds/wave/step; 6-buffer ring (24KB), steady
// vmcnt(4); 1 barrier/step. B panel (20 x bf16x8 = 80 VGPR) asm-pinned so the
// compiler cannot rematerialize the loads inside the K-loop.
#define GLOAD16(gp, lp) __builtin_amdgcn_global_load_lds( \
    (const __attribute__((address_space(1))) unsigned int*)(gp), \
    (__attribute__((address_space(3))) unsigned int*)(lp), 16, 0, 0)

// MODE 0: P[row*NPJ+col] = bf16(acc)
// MODE 1: nv = vbf_old + gelu(acc + bias[col]); last? out=fp32(nv) : vbf=bf16(nv)
template<int MODE>
__global__ __launch_bounds__(256, 2) void gemm_lo(
    const unsigned short* __restrict__ Ab,
    const unsigned short* __restrict__ Bt,
    unsigned short* __restrict__ P,
    float* __restrict__ outv, unsigned short* __restrict__ vbf,
    const float* __restrict__ bias, int last)
{
    __shared__ unsigned short smem[12288];         // 24576 B
    unsigned short* Alds = smem;                   // ring: 6 x 2048 shorts

    const int tid  = threadIdx.x;
    const int lane = tid & 63;
    const int wid  = tid >> 6;

    // bijective XCD swizzle (m204)
    const int gx   = gridDim.x;
    const int nwg  = gx * gridDim.y;
    const int flat = blockIdx.y * gx + blockIdx.x;
    const int q = nwg >> 3, r = nwg & 7;
    const int xcd = flat & 7, off = flat >> 3;
    const int lid = (xcd < r ? xcd * (q + 1) : r * (q + 1) + (xcd - r) * q) + off;
    const int brow = (lid / gx) * 64;
    const int bcol = (lid % gx) * 128;
    const int wn   = wid * 32;

    f32x4 acc[4][2];
    #pragma unroll
    for (int i = 0; i < 4; ++i)
        #pragma unroll
        for (int j = 0; j < 2; ++j)
            #pragma unroll
            for (int rr = 0; rr < 4; ++rr) acc[i][j][rr] = 0.f;

    // ---- B panel -> registers, PINNED (compiler cannot rematerialize) ----
    bf16x8 bfr[NTK][2];
    {
        const unsigned short* Bb =
            Bt + (size_t)(bcol + wn + (lane & 15)) * KP + (lane >> 4) * 8;
        #pragma unroll
        for (int t = 0; t < NTK; ++t) {
            bfr[t][0] = *((const bf16x8*)(Bb + t * 32));
            bfr[t][1] = *((const bf16x8*)(Bb + (size_t)16 * KP + t * 32));
        }
        #pragma unroll
        for (int t = 0; t < NTK; ++t)
            asm volatile("" : "+v"(bfr[t][0]), "+v"(bfr[t][1]));
    }

    // per-thread A staging coords (chunk = tid; 64 rows x 4 chunks of 16B)
    const int arow = tid >> 2;
    const int ac   = (tid & 3) ^ ((arow >> 1) & 3);   // swizzled source chunk
    const unsigned short* asrc = Ab + (size_t)(brow + arow) * KP + ac * 8;

    // prologue: stage A tiles 0..4 (1 vmem op per wave per tile)
    #pragma unroll
    for (int t = 0; t < 5; ++t)
        GLOAD16(asrc + t * 32, Alds + (t % 6) * 2048 + wid * 512);

    #pragma unroll
    for (int t = 0; t < NTK; ++t) {
        unsigned short* Alc = Alds + (t % 6) * 2048;
        if (t <= NTK - 5) {
            asm volatile("s_waitcnt vmcnt(4)" ::: "memory");
        } else if (t == NTK - 4) {
            asm volatile("s_waitcnt vmcnt(3)" ::: "memory");
        } else if (t == NTK - 3) {
            asm volatile("s_waitcnt vmcnt(2)" ::: "memory");
        } else if (t == NTK - 2) {
            asm volatile("s_waitcnt vmcnt(1)" ::: "memory");
        } else {
            asm volatile("s_waitcnt vmcnt(0)" ::: "memory");
        }
        __builtin_amdgcn_s_barrier();
        // stage t+5 into buf (t+5)%6 = (t-1)%6: safe, barrier implies iter t-1
        // reads completed on all waves
        if (t + 5 < NTK)
            GLOAD16(asrc + (t + 5) * 32, Alds + ((t + 5) % 6) * 2048 + wid * 512);

        bf16x8 af[4];
        #pragma unroll
        for (int mi = 0; mi < 4; ++mi) {
            int row = mi * 16 + (lane & 15);
            af[mi] = *((const bf16x8*)&Alc[row * 32 + (((lane >> 4) ^ ((row >> 1) & 3)) * 8)]);
        }
        __builtin_amdgcn_s_setprio(1);
        #pragma unroll
        for (int mi = 0; mi < 4; ++mi)
            #pragma unroll
            for (int nj = 0; nj < 2; ++nj)
                acc[mi][nj] = __builtin_amdgcn_mfma_f32_16x16x32_bf16(
                    af[mi], bfr[t][nj], acc[mi][nj], 0, 0, 0);
        __builtin_amdgcn_s_setprio(0);
    }
    __syncthreads();   // all staging drained; ring reusable as per-wave bounces

    if (MODE == 0) {
        // per-wave bf16 bounce [64][36] = 2304 shorts at smem + wid*2304
        unsigned short* sb = &smem[wid * 2304];
        #pragma unroll
        for (int mi = 0; mi < 4; ++mi)
            #pragma unroll
            for (int nj = 0; nj < 2; ++nj)
                #pragma unroll
                for (int rr = 0; rr < 4; ++rr) {
                    int row = mi * 16 + ((lane >> 4) << 2) + rr;
                    sb[row * 36 + nj * 16 + (lane & 15)] = f2bf(acc[mi][nj][rr]);
                }
        #pragma unroll
        for (int i = 0; i < 4; ++i) {
            int row = i * 16 + (lane >> 2);
            bf16x8 v = *((const bf16x8*)&sb[row * 36 + (lane & 3) * 8]);
            *((bf16x8*)&P[(size_t)(brow + row) * NPJ + bcol + wn + (lane & 3) * 8]) = v;
        }
    } else {
        // per-wave fp32 bounce [32][36] = 4608B, two 32-row passes
        float* fb = (float*)&smem[wid * 2304];
        const int gc = bcol + wn + (lane & 7) * 4;
        #pragma unroll
        for (int h = 0; h < 2; ++h) {
            #pragma unroll
            for (int mi2 = 0; mi2 < 2; ++mi2)
                #pragma unroll
                for (int nj = 0; nj < 2; ++nj)
                    #pragma unroll
                    for (int rr = 0; rr < 4; ++rr) {
                        int row32 = mi2 * 16 + ((lane >> 4) << 2) + rr;
                        fb[row32 * 36 + nj * 16 + (lane & 15)] = acc[h * 2 + mi2][nj][rr];
                    }
            #pragma unroll
            for (int i = 0; i < 4; ++i) {
                int row32 = i * 8 + (lane >> 3);
                int grow = brow + h * 32 + row32;
                float4 vv = *((const float4*)&fb[row32 * 36 + (lane & 7) * 4]);
                if (grow < NND) {
                    if (gc + 4 <= DD) {
                        float4 bv = *((const float4*)&bias[gc]);
                        bf16x4 old = *((const bf16x4*)&vbf[(size_t)grow * KP + gc]);
                        float4 nv;
                        nv.x = bf2f((unsigned short)old[0]) + gelu_exact(vv.x + bv.x);
                        nv.y = bf2f((unsigned short)old[1]) + gelu_exact(vv.y + bv.y);
                        nv.z = bf2f((unsigned short)old[2]) + gelu_exact(vv.z + bv.z);
                        nv.w = bf2f((unsigned short)old[3]) + gelu_exact(vv.w + bv.w);
                        if (last) {
                            *((float4*)&outv[(size_t)grow * DD + gc]) = nv;
                        } else {
                            bf16x4 o;
                            o[0] = (short)f2bf(nv.x); o[1] = (short)f2bf(nv.y);
                            o[2] = (short)f2bf(nv.z); o[3] = (short)f2bf(nv.w);
                            *((bf16x4*)&vbf[(size_t)grow * KP + gc]) = o;
                        }
                    } else {
                        #pragma unroll
                        for (int j = 0; j < 4; ++j) {
                            int ccc = gc + j;
                            if (ccc < DD) {
                                float vj = (j == 0) ? vv.x : (j == 1) ? vv.y
                                         : (j == 2) ? vv.z : vv.w;
                                size_t vidx = (size_t)grow * KP + ccc;
                                float nv = bf2f(vbf[vidx]) + gelu_exact(vj + bias[ccc]);
                                if (last) outv[(size_t)grow * DD + ccc] = nv;
                                else      vbf[vidx] = f2bf(nv);
                            }
                        }
                    }
                }
            }
        }
    }
}

extern "C" void kernel_launch(void* const* d_in, const int* in_sizes, int n_in,
                              void* d_out, int out_size, void* d_ws, size_t ws_size,
                              hipStream_t stream) {
    const float* x  = (const float*)d_in[0];
    const int*   ei = (const int*)  d_in[1];
    const float* Wr = (const float*)d_in[2];
    const float* br = (const float*)d_in[3];
    const float* Wc = (const float*)d_in[4];
    const float* bc = (const float*)d_in[5];
    const float* Wa = (const float*)d_in[6];
    const float* ba = (const float*)d_in[7];
    float* out = (float*)d_out;

    const size_t P_elems   = (size_t)MPAD * NPJ;   // bf16
    const size_t RC_elems  = (size_t)MPAD * KP;    // bf16
    const size_t V_elems   = (size_t)MPAD * KP;    // bf16
    const size_t Bt_elems  = (size_t)LL * NPJ * KP;
    const size_t Wat_elems = (size_t)NUP * KP;

    unsigned short* P   = (unsigned short*)d_ws;
    unsigned short* RC  = P + P_elems;
    unsigned short* vbf = RC + RC_elems;
    unsigned short* Bt  = vbf + V_elems;
    unsigned short* Wat = Bt + Bt_elems;
    int* deg  = (int*)(Wat + Wat_elems);
    int* off  = deg + 2 * SCN;
    int* curp = off + 2 * SCN;
    int* adj  = curp + 2 * SCN;
    int* bsum = adj + 2 * EE;
    const size_t need = (char*)(bsum + 128) - (char*)d_ws;
    if (ws_size < need) return;  // visible fail (output stays poisoned)

    pack_w<<<2880, 256, 0, stream>>>(Wr, Wc, Wa, Bt, Wat);
    init_vbf<<<(int)((V_elems / 8 + 255) / 256), 256, 0, stream>>>(x, vbf);

    const int* src = ei;
    const int* dst = ei + EE;

    hipMemsetAsync(deg, 0, 2 * SCN * sizeof(int), stream);
    hist_deg<<<(EE + 255) / 256, 256, 0, stream>>>(src, dst, deg);
    scanA<<<dim3(NB, 2), 256, 0, stream>>>(deg, off, bsum);
    scanB<<<1, 256, 0, stream>>>(bsum);
    scanC<<<dim3(NB, 2), 256, 0, stream>>>(off, bsum, curp);
    fill_adj<<<(EE + 255) / 256, 256, 0, stream>>>(src, dst, curp, adj);

    dim3 gproj(NPJ / 128, MPAD / 64);   // (5, 1564)
    dim3 gupd (NUP / 128, MPAD / 64);   // (3, 1564)
    dim3 gagg (MPAD / 4, 2);

    for (int l = 0; l < LL; ++l) {
        gemm_lo<0><<<gproj, 256, 0, stream>>>(
            vbf, Bt + (size_t)l * NPJ * KP, P, nullptr, nullptr, nullptr, 0);
        aggregate<<<gagg, 256, 0, stream>>>(
            off, adj, P, br + (size_t)l * HH, bc + (size_t)l * HH, RC);
        gemm_lo<1><<<gupd, 256, 0, stream>>>(
            RC, Wat, nullptr, out, vbf, ba, (l == LL - 1) ? 1 : 0);
    }
}